// Round 2
// baseline (665.556 us; speedup 1.0000x reference)
//
#include <hip/hip_runtime.h>
#include <math.h>

// K0: segment start offsets from sorted segment ids.
// segstart[b] = first n with seg[n] >= b ; segstart[B] = N. Covers empty segs.
__global__ __launch_bounds__(256) void k_segstart(
        const int* __restrict__ seg, int* __restrict__ segstart, int N, int B) {
    int i = blockIdx.x * blockDim.x + threadIdx.x;
    if (i >= N) return;
    int s = seg[i];
    int p = (i == 0) ? -1 : seg[i - 1];
    for (int bb = p + 1; bb <= s; ++bb) segstart[bb] = i;
    if (i == N - 1)
        for (int bb = s + 1; bb <= B; ++bb) segstart[bb] = N;
}

// ---- cross-lane 32-sum: 4 DPP VALU adds + 1 ds_swizzle (xor16) ----
// After xor1,xor2 the quad is uniform, so row_half_mirror (i^7) == xor4;
// after that the 8-group is uniform, so row_mirror (i^15) == xor8.
template <int CTRL>
__device__ __forceinline__ float dpp_add(float v) {
    int sh = __builtin_amdgcn_update_dpp(0, __float_as_int(v), CTRL, 0xF, 0xF,
                                         false);
    return v + __int_as_float(sh);
}
__device__ __forceinline__ float halfwave_sum(float v) {
    v = dpp_add<0xB1>(v);   // quad_perm [1,0,3,2]  : xor1
    v = dpp_add<0x4E>(v);   // quad_perm [2,3,0,1]  : xor2
    v = dpp_add<0x141>(v);  // row_half_mirror      : xor4 (quads uniform)
    v = dpp_add<0x140>(v);  // row_mirror           : xor8 (8-grps uniform)
    int sw = __builtin_amdgcn_ds_swizzle(__float_as_int(v), 0x401F);  // xor16
    return v + __int_as_float(sw);
}

// K1: one block per segment. 256 threads = 8 row-groups x 32 column-lanes.
// Single streaming pass over feat. Main loop: 8 rows/group per iteration,
// unguarded loads (full 64-row chunks), 8 interleaved butterfly chains,
// batched-max online softmax update (one rescale + 8 independent exps).
// Raw gate g goes to workspace; K2 emits alpha.
__global__ __launch_bounds__(256, 4) void k_pool(
        const float* __restrict__ feat, const float* __restrict__ w,
        const float* __restrict__ bptr, const int* __restrict__ segstart,
        float* __restrict__ gbuf, float* __restrict__ Mbuf,
        float* __restrict__ invbuf, float* __restrict__ readout) {
    int b = blockIdx.x;
    int start = segstart[b], end = segstart[b + 1];
    int t = threadIdx.x, rg = t >> 5, cl = t & 31;

    const float4 w4 = ((const float4*)w)[cl];
    const float bias = bptr[0];
    const float4* featv = (const float4*)feat;

    float m = -INFINITY, s = 0.0f;
    float4 acc = make_float4(0.0f, 0.0f, 0.0f, 0.0f);

    const int len = end - start;
    const int nfull = len >> 6;  // full 64-row chunks
    // row (start+rg) base pointer; row r is rowp + r*32 float4s
    const float4* rowp = featv + (size_t)(start + rg) * 32 + cl;
    const bool cl0 = (cl == 0);

    float4 f[8], p[8];

#define PROCESS8(rowbase)                                                     \
    do {                                                                      \
        float g[8];                                                           \
        _Pragma("unroll") for (int j = 0; j < 8; ++j)                         \
            g[j] = f[j].x * w4.x + f[j].y * w4.y + f[j].z * w4.z +            \
                   f[j].w * w4.w;                                             \
        _Pragma("unroll") for (int j = 0; j < 8; ++j)                         \
            g[j] = dpp_add<0xB1>(g[j]);                                       \
        _Pragma("unroll") for (int j = 0; j < 8; ++j)                         \
            g[j] = dpp_add<0x4E>(g[j]);                                       \
        _Pragma("unroll") for (int j = 0; j < 8; ++j)                         \
            g[j] = dpp_add<0x141>(g[j]);                                      \
        _Pragma("unroll") for (int j = 0; j < 8; ++j)                         \
            g[j] = dpp_add<0x140>(g[j]);                                      \
        _Pragma("unroll") for (int j = 0; j < 8; ++j) {                       \
            int sw = __builtin_amdgcn_ds_swizzle(__float_as_int(g[j]),        \
                                                 0x401F);                     \
            g[j] = g[j] + __int_as_float(sw) + bias;                          \
        }                                                                     \
        if (cl0) {                                                            \
            _Pragma("unroll") for (int j = 0; j < 8; ++j)                     \
                gbuf[(rowbase) + 8 * j] = g[j];                               \
        }                                                                     \
        float gm = fmaxf(fmaxf(fmaxf(g[0], g[1]), fmaxf(g[2], g[3])),         \
                         fmaxf(fmaxf(g[4], g[5]), fmaxf(g[6], g[7])));        \
        if (gm > m) {                                                         \
            float r = __expf(m - gm); /* exp(-inf)=0 on first chunk */        \
            s *= r;                                                           \
            acc.x *= r; acc.y *= r; acc.z *= r; acc.w *= r;                   \
            m = gm;                                                           \
        }                                                                     \
        float e[8];                                                           \
        _Pragma("unroll") for (int j = 0; j < 8; ++j)                         \
            e[j] = __expf(g[j] - m);                                          \
        s += ((e[0] + e[1]) + (e[2] + e[3])) +                                \
             ((e[4] + e[5]) + (e[6] + e[7]));                                 \
        _Pragma("unroll") for (int j = 0; j < 8; ++j) {                       \
            acc.x += f[j].x * e[j]; acc.y += f[j].y * e[j];                   \
            acc.z += f[j].z * e[j]; acc.w += f[j].w * e[j];                   \
        }                                                                     \
    } while (0)

    if (nfull > 0) {
        #pragma unroll
        for (int j = 0; j < 8; ++j) f[j] = rowp[(size_t)j * 256];  // 8 rows*32
        for (int it = 1; it < nfull; ++it) {
            const float4* nxt = rowp + (size_t)it * 2048;  // +64 rows
            #pragma unroll
            for (int j = 0; j < 8; ++j) p[j] = nxt[(size_t)j * 256];
            PROCESS8(start + rg + (it - 1) * 64);
            #pragma unroll
            for (int j = 0; j < 8; ++j) f[j] = p[j];
        }
        PROCESS8(start + rg + (nfull - 1) * 64);
    }

    // guarded tail: remaining (< 64) rows, one row per group per step
    for (int n = start + nfull * 64 + rg; n < end; n += 8) {
        float4 ft = featv[(size_t)n * 32 + cl];
        float g = halfwave_sum(ft.x * w4.x + ft.y * w4.y + ft.z * w4.z +
                               ft.w * w4.w) + bias;
        if (cl0) gbuf[n] = g;
        if (g > m) {
            float r = __expf(m - g);
            s *= r;
            acc.x *= r; acc.y *= r; acc.z *= r; acc.w *= r;
            m = g;
        }
        float e = __expf(g - m);
        s += e;
        acc.x += ft.x * e; acc.y += ft.y * e; acc.z += ft.z * e;
        acc.w += ft.w * e;
    }

    // ---- combine the 8 row-groups ----
    __shared__ float mred[8], sred[8];
    if (cl0) { mred[rg] = m; sred[rg] = s; }
    __syncthreads();
    float M = -INFINITY;
    #pragma unroll
    for (int g2 = 0; g2 < 8; ++g2) M = fmaxf(M, mred[g2]);
    float S = 0.0f;
    #pragma unroll
    for (int g2 = 0; g2 < 8; ++g2)
        if (sred[g2] > 0.0f) S += sred[g2] * __expf(mred[g2] - M);
    const float inv = (S > 0.0f) ? 1.0f / S : 0.0f;

    // rescale this group's accumulator to the global max (guard empty group)
    float r = (s > 0.0f) ? __expf(m - M) : 0.0f;
    acc.x *= r; acc.y *= r; acc.z *= r; acc.w *= r;

    __shared__ float4 red[256];
    red[t] = acc;
    __syncthreads();
    #pragma unroll
    for (int off = 4; off >= 1; off >>= 1) {
        if (rg < off) {
            float4 o = red[t + off * 32];
            red[t].x += o.x; red[t].y += o.y; red[t].z += o.z; red[t].w += o.w;
        }
        __syncthreads();
    }
    if (rg == 0) {
        float4 o = red[t];
        o.x *= inv; o.y *= inv; o.z *= inv; o.w *= inv;
        ((float4*)(readout + (size_t)b * 128))[cl] = o;
    }
    if (t == 0) { Mbuf[b] = M; invbuf[b] = inv; }
}

// K2: alpha[n] = exp(g[n] - M[seg[n]]) * inv[seg[n]]. ~12 MB traffic.
__global__ __launch_bounds__(256) void k_alpha(
        const float* __restrict__ gbuf, const int* __restrict__ seg,
        const float* __restrict__ Mbuf, const float* __restrict__ invbuf,
        float* __restrict__ alpha, int N) {
    int i = blockIdx.x * blockDim.x + threadIdx.x;
    int i4 = i * 4;
    if (i4 + 3 < N) {
        float4 g = ((const float4*)gbuf)[i];
        int4 sv = ((const int4*)seg)[i];
        float4 a;
        a.x = __expf(g.x - Mbuf[sv.x]) * invbuf[sv.x];
        a.y = __expf(g.y - Mbuf[sv.y]) * invbuf[sv.y];
        a.z = __expf(g.z - Mbuf[sv.z]) * invbuf[sv.z];
        a.w = __expf(g.w - Mbuf[sv.w]) * invbuf[sv.w];
        ((float4*)alpha)[i] = a;
    } else if (i4 < N) {
        for (int k = i4; k < N; ++k) {
            int sb = seg[k];
            alpha[k] = __expf(gbuf[k] - Mbuf[sb]) * invbuf[sb];
        }
    }
}

extern "C" void kernel_launch(void* const* d_in, const int* in_sizes, int n_in,
                              void* d_out, int out_size, void* d_ws, size_t ws_size,
                              hipStream_t stream) {
    const float* feat  = (const float*)d_in[0];
    const float* wgate = (const float*)d_in[1];
    const float* bgate = (const float*)d_in[2];
    const int*   seg   = (const int*)d_in[3];

    const int N = in_sizes[3];              // 1,000,000 nodes
    const int D = in_sizes[1];              // 128
    const int B = (out_size - N) / D;       // 1024 graphs

    float* readout = (float*)d_out;                    // [B,128]
    float* alpha   = (float*)d_out + (size_t)B * 128;  // [N]

    // workspace layout: segstart | Mbuf | invbuf | gbuf (all 256B-aligned)
    int* segstart = (int*)d_ws;
    size_t off = (((size_t)(B + 1) * 4) + 255) & ~(size_t)255;
    float* Mbuf = (float*)((char*)d_ws + off);
    float* invbuf = Mbuf + B;
    size_t off2 = (off + (size_t)2 * B * 4 + 255) & ~(size_t)255;
    float* gbuf = (float*)((char*)d_ws + off2);

    k_segstart<<<(N + 255) / 256, 256, 0, stream>>>(seg, segstart, N, B);
    k_pool<<<B, 256, 0, stream>>>(feat, wgate, bgate, segstart,
                                  gbuf, Mbuf, invbuf, readout);
    int threads4 = (N + 3) / 4;
    k_alpha<<<(threads4 + 255) / 256, 256, 0, stream>>>(gbuf, seg, Mbuf, invbuf,
                                                        alpha, N);
}